// Round 12
// baseline (1559.931 us; speedup 1.0000x reference)
//
#include <hip/hip_runtime.h>

// ---- problem constants ----
constexpr int NT   = 2048;   // tokens
constexpr int HD   = 512;    // hidden = HQ*D = HKV*D
constexpr int MBLK = 4096;   // 16^3 compression block slots
constexpr int SBLK = 512;    // 8^3 selection block slots
constexpr int NW3  = 729;    // 9^3 shifted windows
constexpr int KPAD = 2048;   // padded key stride for ckT4 / S rows
#define NEGI (-1e30f)

// =========================================================================
// token prep: coords decode, ids, bucket counts
// =========================================================================
__global__ __launch_bounds__(256) void token_prep(
    const int* __restrict__ cf, int* __restrict__ bid, int* __restrict__ sbid,
    int* __restrict__ wid, int* __restrict__ ibid, int* __restrict__ cnt,
    int* __restrict__ selcnt, int* __restrict__ wincnt) {
  int n = blockIdx.x * 256 + threadIdx.x;
  if (n >= NT) return;
  int c = cf[n];
  int x = c >> 12, y = (c >> 6) & 63, z = c & 63;
  int b  = ((x >> 2) << 8) | ((y >> 2) << 4) | (z >> 2);
  int sb = ((x >> 3) << 6) | ((y >> 3) << 3) | (z >> 3);
  int w  = ((x + 4) >> 3) * 81 + ((y + 4) >> 3) * 9 + ((z + 4) >> 3);
  int ib = ((x & 3) << 4) | ((y & 3) << 2) | (z & 3);
  bid[n] = b; sbid[n] = sb; wid[n] = w; ibid[n] = ib;
  atomicAdd(&cnt[b], 1);
  atomicAdd(&selcnt[sb], 1);
  atomicAdd(&wincnt[w], 1);
}

// =========================================================================
// single-block scans: occupied-block compaction + bucket offsets
// =========================================================================
__global__ __launch_bounds__(1024) void scan_all(
    const int* __restrict__ cnt, int* __restrict__ occ_m, int* __restrict__ inv,
    int* __restrict__ noccPtr,
    const int* __restrict__ selcnt, int* __restrict__ seloff, int* __restrict__ selpos,
    const int* __restrict__ wincnt, int* __restrict__ winoff, int* __restrict__ winpos) {
  __shared__ int buf[1024];
  int t = threadIdx.x;

  // ---- phase 1: compaction scan over MBLK=4096 (4 per thread) ----
  int base = t * 4;
  int f0 = cnt[base + 0] > 0, f1 = cnt[base + 1] > 0,
      f2 = cnt[base + 2] > 0, f3 = cnt[base + 3] > 0;
  int s = f0 + f1 + f2 + f3;
  buf[t] = s;
  __syncthreads();
  for (int off = 1; off < 1024; off <<= 1) {
    int add = (t >= off) ? buf[t - off] : 0;
    __syncthreads();
    buf[t] += add;
    __syncthreads();
  }
  int pos = buf[t] - s;
  if (f0) { occ_m[pos] = base + 0; inv[base + 0] = pos; pos++; }
  if (f1) { occ_m[pos] = base + 1; inv[base + 1] = pos; pos++; }
  if (f2) { occ_m[pos] = base + 2; inv[base + 2] = pos; pos++; }
  if (f3) { occ_m[pos] = base + 3; inv[base + 3] = pos; pos++; }
  if (t == 1023) noccPtr[0] = buf[1023];
  __syncthreads();

  // ---- phase 2: selection buckets (512) ----
  int v = (t < SBLK) ? selcnt[t] : 0;
  buf[t] = v;
  __syncthreads();
  for (int off = 1; off < 1024; off <<= 1) {
    int add = (t >= off) ? buf[t - off] : 0;
    __syncthreads();
    buf[t] += add;
    __syncthreads();
  }
  if (t < SBLK) {
    seloff[t + 1] = buf[t];
    selpos[t] = buf[t] - v;
    if (t == 0) seloff[0] = 0;
  }
  __syncthreads();

  // ---- phase 3: window buckets (729) ----
  int v2 = (t < NW3) ? wincnt[t] : 0;
  buf[t] = v2;
  __syncthreads();
  for (int off = 1; off < 1024; off <<= 1) {
    int add = (t >= off) ? buf[t - off] : 0;
    __syncthreads();
    buf[t] += add;
    __syncthreads();
  }
  if (t < NW3) {
    winoff[t + 1] = buf[t];
    winpos[t] = buf[t] - v2;
    if (t == 0) winoff[0] = 0;
  }
}

// =========================================================================
// scatter tokens into buckets
// =========================================================================
__global__ __launch_bounds__(256) void scatter(
    const int* __restrict__ sbid, const int* __restrict__ wid,
    int* __restrict__ selpos, int* __restrict__ winpos,
    int* __restrict__ sellist, int* __restrict__ winlist) {
  int n = blockIdx.x * 256 + threadIdx.x;
  if (n >= NT) return;
  int p = atomicAdd(&selpos[sbid[n]], 1);
  sellist[p] = n;
  int p2 = atomicAdd(&winpos[wid[n]], 1);
  winlist[p2] = n;
}

// =========================================================================
// f32 GEMM body: C[rows,512] = A[rows,512] @ B[512,512] (64x64 tile)
// kk-major LDS: inner loop = 2x ds_read_b128 per 16 FMAs.
// =========================================================================
__device__ __forceinline__ void gemm_body(
    const float* __restrict__ A, const float* __restrict__ B,
    float* __restrict__ C, int nrows) {
  int rb = blockIdx.x, cb = blockIdx.y;
  int row0 = rb * 64, col0 = cb * 64;
  if (row0 >= nrows) return;
  __shared__ float As[16][68];   // [kk][row]
  __shared__ float Bs[16][68];   // [kk][col]
  int t = threadIdx.x;
  int tx = t & 15, ty = t >> 4;
  float acc[4][4] = {};
  for (int k0 = 0; k0 < 512; k0 += 16) {
    {
      int idx = t * 4; int r = idx >> 4; int kk = idx & 15;
      int gr = row0 + r;
      float4 va = (gr < nrows) ? *(const float4*)(A + (size_t)gr * 512 + k0 + kk)
                               : make_float4(0.f, 0.f, 0.f, 0.f);
      As[kk + 0][r] = va.x; As[kk + 1][r] = va.y;
      As[kk + 2][r] = va.z; As[kk + 3][r] = va.w;
    }
    {
      int idx = t * 4; int kk = idx >> 6; int cc = idx & 63;
      float4 vb = *(const float4*)(B + (size_t)(k0 + kk) * 512 + col0 + cc);
      *(float4*)(&Bs[kk][cc]) = vb;
    }
    __syncthreads();
#pragma unroll
    for (int kk = 0; kk < 16; ++kk) {
      float4 af = *(const float4*)(&As[kk][ty * 4]);
      float4 bf = *(const float4*)(&Bs[kk][tx * 4]);
      acc[0][0] += af.x * bf.x; acc[0][1] += af.x * bf.y; acc[0][2] += af.x * bf.z; acc[0][3] += af.x * bf.w;
      acc[1][0] += af.y * bf.x; acc[1][1] += af.y * bf.y; acc[1][2] += af.y * bf.z; acc[1][3] += af.y * bf.w;
      acc[2][0] += af.z * bf.x; acc[2][1] += af.z * bf.y; acc[2][2] += af.z * bf.z; acc[2][3] += af.z * bf.w;
      acc[3][0] += af.w * bf.x; acc[3][1] += af.w * bf.y; acc[3][2] += af.w * bf.z; acc[3][3] += af.w * bf.w;
    }
    __syncthreads();
  }
#pragma unroll
  for (int i = 0; i < 4; ++i) {
    int r = row0 + ty * 4 + i;
    if (r < nrows) {
#pragma unroll
      for (int j = 0; j < 4; ++j)
        C[(size_t)r * 512 + col0 + tx * 4 + j] = acc[i][j];
    }
  }
}

__global__ __launch_bounds__(256) void gemm512(
    const float* __restrict__ A, const float* __restrict__ B, float* __restrict__ C,
    int nrowsConst) {
  gemm_body(A, B, C, nrowsConst);
}

// batched: shared A, 3 B/C pairs selected by blockIdx.z (q/k/v projections)
__global__ __launch_bounds__(256) void gemm512_b3(
    const float* __restrict__ A,
    const float* __restrict__ B0, const float* __restrict__ B1, const float* __restrict__ B2,
    float* __restrict__ C0, float* __restrict__ C1, float* __restrict__ C2) {
  const float* B = blockIdx.z == 0 ? B0 : (blockIdx.z == 1 ? B1 : B2);
  float* C = blockIdx.z == 0 ? C0 : (blockIdx.z == 1 ? C1 : C2);
  gemm_body(A, B, C, NT);
}

// batched: 2 independent GEMMs (ck/cv projections), rows from device count
__global__ __launch_bounds__(256) void gemm512_b2(
    const float* __restrict__ A0, const float* __restrict__ A1,
    const float* __restrict__ B0, const float* __restrict__ B1,
    float* __restrict__ C0, float* __restrict__ C1,
    const int* __restrict__ nrowsPtr) {
  const float* A = blockIdx.z == 0 ? A0 : A1;
  const float* B = blockIdx.z == 0 ? B0 : B1;
  float* C = blockIdx.z == 0 ? C0 : C1;
  gemm_body(A, B, C, *nrowsPtr);
}

// =========================================================================
// gate: sigmoid(feats @ Wg)   Wg:[512,3]
// =========================================================================
__global__ __launch_bounds__(256) void gatek(
    const float* __restrict__ feats, const float* __restrict__ Wg,
    float* __restrict__ gates) {
  int idx = blockIdx.x * 256 + threadIdx.x;
  if (idx >= NT * 3) return;
  int n = idx / 3, g = idx % 3;
  const float* fp = feats + (size_t)n * 512;
  float s = 0.f;
  for (int i = 0; i < 512; ++i) s += fp[i] * Wg[i * 3 + g];
  gates[idx] = 1.f / (1.f + __expf(-s));
}

// =========================================================================
// segment accumulation into compacted block means (pre-division)
// =========================================================================
__global__ __launch_bounds__(256) void accum(
    const float* __restrict__ kf, const float* __restrict__ vf,
    const float* __restrict__ pe, const int* __restrict__ bid,
    const int* __restrict__ ibid, const int* __restrict__ inv,
    float* __restrict__ ksum, float* __restrict__ vsum) {
  int n = blockIdx.x;
  int t = threadIdx.x;
  int i = inv[bid[n]];
  const float* kp = kf + (size_t)n * 512;
  const float* vp = vf + (size_t)n * 512;
  const float* pp = pe + (size_t)ibid[n] * 512;
  float* kd = ksum + (size_t)i * 512;
  float* vd = vsum + (size_t)i * 512;
  atomicAdd(&kd[t], kp[t] + pp[t]);
  atomicAdd(&kd[t + 256], kp[t + 256] + pp[t + 256]);
  atomicAdd(&vd[t], vp[t]);
  atomicAdd(&vd[t + 256], vp[t + 256]);
}

__global__ __launch_bounds__(256) void divide_means(
    float* __restrict__ ksum, float* __restrict__ vsum,
    const int* __restrict__ occ_m, const int* __restrict__ cnt,
    const int* __restrict__ noccPtr, int* __restrict__ sid_key) {
  int idx = blockIdx.x * 256 + threadIdx.x;
  int i = idx >> 9;
  if (i >= *noccPtr) return;
  float rinv = 1.f / (float)cnt[occ_m[i]];
  ksum[idx] *= rinv;
  vsum[idx] *= rinv;
  if ((idx & 511) == 0) {
    int mm2 = occ_m[i];
    sid_key[i] = (((mm2 >> 9) & 7) << 6) | (((mm2 >> 5) & 7) << 3) | ((mm2 >> 1) & 7);
  }
}

// =========================================================================
// transpose compressed keys into ckT4: [dgroup=d/4][key (KPAD stride)][4]
// (float4-loadable per key)
// =========================================================================
__global__ __launch_bounds__(256) void transp(
    const float* __restrict__ src, float* __restrict__ dst,
    const int* __restrict__ noccPtr) {
  __shared__ float tile[64][65];
  int nocc = *noccPtr;
  int k0 = blockIdx.x * 64;   // key tile
  int d0 = blockIdx.y * 64;   // dim tile
  int c = threadIdx.x & 63, r0 = (threadIdx.x >> 6) * 16;
  for (int r = 0; r < 16; ++r) {
    int key = k0 + r0 + r;
    tile[r0 + r][c] = (key < nocc) ? src[(size_t)key * 512 + d0 + c] : 0.f;
  }
  __syncthreads();
  // lane c = key; write 4 dim-groups of this 64-dim tile
  float4* dst4 = (float4*)dst;
  int gl0 = (threadIdx.x >> 6) * 4;
#pragma unroll
  for (int gg = 0; gg < 4; ++gg) {
    int gl = gl0 + gg;                   // local dim-group 0..15
    float4 v = make_float4(tile[c][gl * 4 + 0], tile[c][gl * 4 + 1],
                           tile[c][gl * 4 + 2], tile[c][gl * 4 + 3]);
    dst4[(size_t)(d0 / 4 + gl) * KPAD + k0 + c] = v;
  }
}

// =========================================================================
// cattn merged kernel (cqkpv) v2: 4 tokens/block, 2-key register blocking,
// float4 ck loads. Acc state = 24 regs (sa/sb/pa/pb/lacc/o of 4) — SAME
// register class as the R9-proven body (R10's spill was 8-tok x 2-key =
// 48 acc regs; halving tokens pays for the key blocking).
// Per 128-key tile: QK qv LDS reads halve (64 b128), ck VMEM 32 b128.
// Stores e = exp(sc) to S (8-tok-group layout preserved for cselfin),
// unnormalized PV partials per key-quarter + l partials.
// grid (512 groups, 4 quarters), 512 thr = 8 waves = 8 heads.
// =========================================================================
__global__ __launch_bounds__(512) void cqkpv(
    const float* __restrict__ q, const float* __restrict__ ckT4,
    const float* __restrict__ cv, const int* __restrict__ noccPtr,
    float* __restrict__ S, float* __restrict__ lpart,
    float* __restrict__ opart) {
  __shared__ float qlds[4 * 512];       // 8 KB (tok-major)
  __shared__ float pmat[8][4][128];     // 16 KB
  __shared__ float lred[8][4];
  const int g = blockIdx.x;             // 4-token group
  const int n0 = g * 4;
  const int quarter = blockIdx.y;
  const int t = threadIdx.x;
  const int nocc = *noccPtr;
  const int qbeg = (nocc * quarter) >> 2;
  const int qend = (nocc * (quarter + 1)) >> 2;
  const int l = t & 63;
  const int h = __builtin_amdgcn_readfirstlane(t >> 6);

  for (int idx = t; idx < 2048; idx += 512)
    qlds[idx] = q[(size_t)n0 * 512 + idx];
  __syncthreads();

  const float4* ckp = (const float4*)ckT4 + (size_t)(h * 16) * KPAD;
  const float* qh = qlds + h * 64;      // + tok*512 + d
  // S row layout identical to R11 (8-token groups): row = (n>>3)*64 + h*8 + (n&7)
  float* Srow = S + ((size_t)(g >> 1) * 64 + h * 8 + (g & 1) * 4) * KPAD;

  float lacc[4] = {0.f, 0.f, 0.f, 0.f};
  float o[4]    = {0.f, 0.f, 0.f, 0.f};

  for (int i0 = qbeg; i0 < qend; i0 += 128) {
    int lim = qend - i0; lim = lim > 128 ? 128 : lim;
    int ia = i0 + l;
    int ibRaw = ia + 64;
    bool va = ia < qend, vb = ibRaw < qend;
    int iA = va ? ia : (qend - 1);
    int iB = vb ? ibRaw : iA;
    float sa[4] = {0.f, 0.f, 0.f, 0.f};
    float sb[4] = {0.f, 0.f, 0.f, 0.f};
#pragma unroll
    for (int c = 0; c < 16; ++c) {
      float4 ka = ckp[(size_t)c * KPAD + iA];
      float4 kb = ckp[(size_t)c * KPAD + iB];
#pragma unroll
      for (int tok = 0; tok < 4; ++tok) {
        float4 qv = *(const float4*)(qh + tok * 512 + c * 4);
        sa[tok] += ka.x * qv.x + ka.y * qv.y + ka.z * qv.z + ka.w * qv.w;
        sb[tok] += kb.x * qv.x + kb.y * qv.y + kb.z * qv.z + kb.w * qv.w;
      }
    }
    float pa[4], pb[4];
#pragma unroll
    for (int tok = 0; tok < 4; ++tok) {
      pa[tok] = va ? __expf(sa[tok] * 0.125f) : 0.f;
      pb[tok] = vb ? __expf(sb[tok] * 0.125f) : 0.f;
      lacc[tok] += pa[tok] + pb[tok];
      if (va) Srow[(size_t)tok * KPAD + ia] = pa[tok];
      if (vb) Srow[(size_t)tok * KPAD + ibRaw] = pb[tok];
    }
    __syncthreads();   // prior tile's pmat fully consumed
#pragma unroll
    for (int tok = 0; tok < 4; ++tok) {
      pmat[h][tok][l] = pa[tok];
      pmat[h][tok][64 + l] = pb[tok];
    }
    __syncthreads();
    // PV (unnormalized): lane = output dim; wave covers all keys of the tile
    {
      const float* cvp = cv + (size_t)i0 * 512 + h * 64 + l;
      int g4 = lim >> 2;
      for (int gg = 0; gg < g4; ++gg) {
        float v0 = cvp[(size_t)(gg * 4 + 0) * 512];
        float v1 = cvp[(size_t)(gg * 4 + 1) * 512];
        float v2 = cvp[(size_t)(gg * 4 + 2) * 512];
        float v3 = cvp[(size_t)(gg * 4 + 3) * 512];
#pragma unroll
        for (int tok = 0; tok < 4; ++tok) {
          float4 pm = *(const float4*)(&pmat[h][tok][gg * 4]);
          o[tok] += pm.x * v0 + pm.y * v1 + pm.z * v2 + pm.w * v3;
        }
      }
      for (int j = g4 * 4; j < lim; ++j) {
        float v = cvp[(size_t)j * 512];
#pragma unroll
        for (int tok = 0; tok < 4; ++tok) o[tok] += pmat[h][tok][j] * v;
      }
    }
  }

  // l partial reduce across lanes -> lpart[quarter][n][h]
#pragma unroll
  for (int tok = 0; tok < 4; ++tok) {
    float l2 = lacc[tok];
#pragma unroll
    for (int s2 = 32; s2; s2 >>= 1) l2 += __shfl_xor(l2, s2, 64);
    if (l == 0) lred[h][tok] = l2;
  }
  __syncthreads();
  if (t < 32) {
    int h2 = t & 7, tok = t >> 3;
    lpart[((size_t)quarter * NT + n0 + tok) * 8 + h2] = lred[h2][tok];
  }
  // per-quarter unnormalized o partial
#pragma unroll
  for (int tok = 0; tok < 4; ++tok)
    opart[((size_t)quarter * NT + n0 + tok) * 512 + h * 64 + l] = o[tok];
}

// =========================================================================
// cselfin: per 8-token group. rl = 1/l_tot, pools heads over S, segment-sums
// selection scores (LDS atomics), top-8, fused = gate0 * o_un / l.
// =========================================================================
__global__ __launch_bounds__(256) void cselfin(
    const float* __restrict__ S, const float* __restrict__ lpart,
    const float* __restrict__ opart, const int* __restrict__ sid_key,
    const int* __restrict__ noccPtr, const float* __restrict__ gates,
    float* __restrict__ fused, int* __restrict__ topk_out) {
  __shared__ float selsc[8 * 512];   // 16 KB
  __shared__ float rlh[8][8];        // [tok][h]
  const int bx = blockIdx.x, t = threadIdx.x;
  const int n0 = bx * 8;
  const int nocc = *noccPtr;

  for (int idx = t; idx < 4096; idx += 256) selsc[idx] = 0.f;
  if (t < 64) {
    int tok = t >> 3, h = t & 7;
    float lt = 0.f;
#pragma unroll
    for (int qq = 0; qq < 4; ++qq)
      lt += lpart[((size_t)qq * NT + n0 + tok) * 8 + h];
    rlh[tok][h] = 1.f / lt;
  }
  __syncthreads();

  const float* Sb = S + (size_t)bx * 64 * KPAD;   // rows (h*8 + tok)
  for (int tok = 0; tok < 8; ++tok) {
    for (int i0 = 0; i0 < nocc; i0 += 256) {
      int i = i0 + t;
      if (i < nocc) {
        float ps = 0.f;
#pragma unroll
        for (int h = 0; h < 8; ++h)
          ps += Sb[((size_t)h * 8 + tok) * KPAD + i] * rlh[tok][h];
        atomicAdd(&selsc[tok * 512 + sid_key[i]], ps);
      }
    }
  }
  __syncthreads();

  // fused = gate0 * (sum_q o_un) / l_tot
  for (int idx = t; idx < 4096; idx += 256) {
    int tok = idx >> 9, d = idx & 511, h = d >> 6;
    float osum = 0.f;
#pragma unroll
    for (int qq = 0; qq < 4; ++qq)
      osum += opart[((size_t)qq * NT + n0 + tok) * 512 + d];
    fused[(size_t)(n0 + tok) * 512 + d] = gates[(n0 + tok) * 3] * osum * rlh[tok][h];
  }

  // top-8 per token: 4 waves x 2 tokens (value desc, index asc ties)
  int w = t >> 6, l = t & 63;
  for (int tk2 = 0; tk2 < 2; ++tk2) {
    int tok = w * 2 + tk2;
    float* sp = selsc + tok * 512;
    float v[8];
#pragma unroll
    for (int r = 0; r < 8; ++r) v[r] = sp[r * 64 + l];
#pragma unroll
    for (int k = 0; k < 8; ++k) {
      float bv = v[0]; int bi = l;
#pragma unroll
      for (int r = 1; r < 8; ++r)
        if (v[r] > bv) { bv = v[r]; bi = r * 64 + l; }
#pragma unroll
      for (int s2 = 32; s2; s2 >>= 1) {
        float ov = __shfl_xor(bv, s2, 64);
        int oi = __shfl_xor(bi, s2, 64);
        if (ov > bv || (ov == bv && oi < bi)) { bv = ov; bi = oi; }
      }
      if (l == 0) topk_out[(n0 + tok) * 8 + k] = bi;
#pragma unroll
      for (int r = 0; r < 8; ++r)
        if (bi == r * 64 + l) v[r] = NEGI;
    }
  }
}

// =========================================================================
// selection + window attention (sparse, bucketed), adds into fused
// =========================================================================
__global__ __launch_bounds__(64) void selwin(
    const float* __restrict__ q, const float* __restrict__ kf,
    const float* __restrict__ vf, const int* __restrict__ topk,
    const int* __restrict__ seloff, const int* __restrict__ sellist,
    const int* __restrict__ winoff, const int* __restrict__ winlist,
    const int* __restrict__ wid_tok, const float* __restrict__ gates,
    float* __restrict__ fused) {
  int n = blockIdx.x, t = threadIdx.x;
  int h = t >> 3, j = t & 7;
  float q8[8];
  const float* qp = q + (size_t)n * 512 + h * 64 + j * 8;
#pragma unroll
  for (int d = 0; d < 8; ++d) q8[d] = qp[d];

  // ---- selection branch ----
  float os[8];
#pragma unroll
  for (int d = 0; d < 8; ++d) os[d] = 0.f;
  float m = NEGI, lsum = 0.f;
  for (int k = 0; k < 8; ++k) {
    int s = topk[n * 8 + k];
    int e0 = seloff[s], e1 = seloff[s + 1];
    for (int idx = e0; idx < e1; ++idx) {
      int tj = sellist[idx];
      const float* kp = kf + (size_t)tj * 512 + h * 64 + j * 8;
      float part = 0.f;
#pragma unroll
      for (int d = 0; d < 8; ++d) part += q8[d] * kp[d];
      part += __shfl_xor(part, 1, 64);
      part += __shfl_xor(part, 2, 64);
      part += __shfl_xor(part, 4, 64);
      float sc = part * 0.125f;
      float nm = fmaxf(m, sc);
      float scale = __expf(m - nm);
      float pv = __expf(sc - nm);
      const float* vp = vf + (size_t)tj * 512 + h * 64 + j * 8;
      lsum = lsum * scale + pv;
#pragma unroll
      for (int d = 0; d < 8; ++d) os[d] = os[d] * scale + pv * vp[d];
      m = nm;
    }
  }
  {
    float rl = (lsum > 0.f) ? 1.f / lsum : 0.f;
#pragma unroll
    for (int d = 0; d < 8; ++d) os[d] *= rl;
  }

  // ---- window branch ----
  float ow[8];
#pragma unroll
  for (int d = 0; d < 8; ++d) ow[d] = 0.f;
  m = NEGI; lsum = 0.f;
  int w = wid_tok[n];
  int e0 = winoff[w], e1 = winoff[w + 1];
  for (int idx = e0; idx < e1; ++idx) {
    int tj = winlist[idx];
    const float* kp = kf + (size_t)tj * 512 + h * 64 + j * 8;
    float part = 0.f;
#pragma unroll
    for (int d = 0; d < 8; ++d) part += q8[d] * kp[d];
    part += __shfl_xor(part, 1, 64);
    part += __shfl_xor(part, 2, 64);
    part += __shfl_xor(part, 4, 64);
    float sc = part * 0.125f;
    float nm = fmaxf(m, sc);
    float scale = __expf(m - nm);
    float pv = __expf(sc - nm);
    const float* vp = vf + (size_t)tj * 512 + h * 64 + j * 8;
    lsum = lsum * scale + pv;
#pragma unroll
    for (int d = 0; d < 8; ++d) ow[d] = ow[d] * scale + pv * vp[d];
    m = nm;
  }
  {
    float rl = (lsum > 0.f) ? 1.f / lsum : 0.f;
#pragma unroll
    for (int d = 0; d < 8; ++d) ow[d] *= rl;
  }

  float g1 = gates[n * 3 + 1], g2 = gates[n * 3 + 2];
  float* fp = fused + (size_t)n * 512 + h * 64 + j * 8;
#pragma unroll
  for (int d = 0; d < 8; ++d) fp[d] += g1 * os[d] + g2 * ow[d];
}

// =========================================================================
// launcher
// =========================================================================
extern "C" void kernel_launch(void* const* d_in, const int* in_sizes, int n_in,
                              void* d_out, int out_size, void* d_ws, size_t ws_size,
                              hipStream_t stream) {
  const float* feats = (const float*)d_in[0];
  const int* coords  = (const int*)d_in[1];
  const float* Wq  = (const float*)d_in[2];
  const float* Wk  = (const float*)d_in[3];
  const float* Wv  = (const float*)d_in[4];
  const float* Wo  = (const float*)d_in[5];
  const float* Wck = (const float*)d_in[6];
  const float* Wcv = (const float*)d_in[7];
  const float* pe  = (const float*)d_in[8];
  const float* Wg  = (const float*)d_in[9];
  float* out = (float*)d_out;

  char* p = (char*)d_ws;
  auto alloc = [&](size_t bytes) -> char* {
    char* r = p;
    p += (bytes + 255) & ~(size_t)255;
    return r;
  };
  float* q     = (float*)alloc((size_t)NT * 512 * 4);
  float* kf    = (float*)alloc((size_t)NT * 512 * 4);
  float* vf    = (float*)alloc((size_t)NT * 512 * 4);
  float* fused = (float*)alloc((size_t)NT * 512 * 4);
  float* zf    = (float*)alloc((size_t)2 * NT * 512 * 4);  // ckbar|cvbar (zeroed)
  float* ckbar = zf;
  float* cvbar = zf + (size_t)NT * 512;
  float* ckc   = (float*)alloc((size_t)NT * 512 * 4);
  float* cvc   = (float*)alloc((size_t)NT * 512 * 4);
  float* ckT   = (float*)alloc((size_t)512 * KPAD * 4);
  float* gates = (float*)alloc((size_t)NT * 3 * 4);
  float* lpart = (float*)alloc((size_t)4 * NT * 8 * 4);
  float* opart = (float*)alloc((size_t)4 * NT * 512 * 4);
  int* zi      = (int*)alloc((size_t)(MBLK + SBLK + NW3) * 4);  // cnt|selcnt|wincnt
  int* cnt = zi;
  int* selcnt = zi + MBLK;
  int* wincnt = zi + MBLK + SBLK;
  int* inv     = (int*)alloc((size_t)MBLK * 4);
  int* occ     = (int*)alloc((size_t)NT * 4);
  int* nocc    = (int*)alloc(4);
  int* bid     = (int*)alloc((size_t)NT * 4);
  int* sbid    = (int*)alloc((size_t)NT * 4);
  int* wid     = (int*)alloc((size_t)NT * 4);
  int* ibid    = (int*)alloc((size_t)NT * 4);
  int* sid_key = (int*)alloc((size_t)NT * 4);
  int* seloff  = (int*)alloc((size_t)(SBLK + 1) * 4);
  int* selpos  = (int*)alloc((size_t)SBLK * 4);
  int* sellist = (int*)alloc((size_t)NT * 4);
  int* winoff  = (int*)alloc((size_t)(NW3 + 1) * 4);
  int* winpos  = (int*)alloc((size_t)NW3 * 4);
  int* winlist = (int*)alloc((size_t)NT * 4);
  int* topk    = (int*)alloc((size_t)NT * 8 * 4);
  // big S buffer last: 256 groups x 64 rows x KPAD f32 = 128 MB
  size_t sbytes = (size_t)(NT / 8) * 64 * KPAD * 4;
  float* S = (float*)alloc(sbytes);

  hipMemsetAsync(zf, 0, (size_t)2 * NT * 512 * 4, stream);
  hipMemsetAsync(zi, 0, (size_t)(MBLK + SBLK + NW3) * 4, stream);

  token_prep<<<8, 256, 0, stream>>>(coords, bid, sbid, wid, ibid, cnt, selcnt, wincnt);
  scan_all<<<1, 1024, 0, stream>>>(cnt, occ, inv, nocc, selcnt, seloff, selpos,
                                   wincnt, winoff, winpos);
  scatter<<<8, 256, 0, stream>>>(sbid, wid, selpos, winpos, sellist, winlist);

  gemm512_b3<<<dim3(32, 8, 3), 256, 0, stream>>>(feats, Wq, Wk, Wv, q, kf, vf);
  gatek<<<24, 256, 0, stream>>>(feats, Wg, gates);

  accum<<<NT, 256, 0, stream>>>(kf, vf, pe, bid, ibid, inv, ckbar, cvbar);
  divide_means<<<4096, 256, 0, stream>>>(ckbar, cvbar, occ, cnt, nocc, sid_key);
  gemm512_b2<<<dim3(32, 8, 2), 256, 0, stream>>>(ckbar, cvbar, Wck, Wcv, ckc, cvc, nocc);
  transp<<<dim3(32, 8), 256, 0, stream>>>(ckc, ckT, nocc);

  cqkpv<<<dim3(512, 4), 512, 0, stream>>>(q, ckT, cvc, nocc, S, lpart, opart);
  cselfin<<<256, 256, 0, stream>>>(S, lpart, opart, sid_key, nocc, gates,
                                   fused, topk);

  selwin<<<NT, 64, 0, stream>>>(q, kf, vf, topk, seloff, sellist, winoff, winlist,
                                wid, gates, fused);
  gemm512<<<dim3(32, 8), 256, 0, stream>>>(fused, Wo, out, NT);
}

// Round 13
// 666.296 us; speedup vs baseline: 2.3412x; 2.3412x over previous
//
#include <hip/hip_runtime.h>

// ---- problem constants ----
constexpr int NT   = 2048;   // tokens
constexpr int HD   = 512;    // hidden = HQ*D = HKV*D
constexpr int MBLK = 4096;   // 16^3 compression block slots
constexpr int SBLK = 512;    // 8^3 selection block slots
constexpr int NW3  = 729;    // 9^3 shifted windows
constexpr int KPAD = 2048;   // padded key stride for ckT4 / S rows
#define NEGI (-1e30f)

// =========================================================================
// token prep: coords decode, ids, bucket counts
// =========================================================================
__global__ __launch_bounds__(256) void token_prep(
    const int* __restrict__ cf, int* __restrict__ bid, int* __restrict__ sbid,
    int* __restrict__ wid, int* __restrict__ ibid, int* __restrict__ cnt,
    int* __restrict__ selcnt, int* __restrict__ wincnt) {
  int n = blockIdx.x * 256 + threadIdx.x;
  if (n >= NT) return;
  int c = cf[n];
  int x = c >> 12, y = (c >> 6) & 63, z = c & 63;
  int b  = ((x >> 2) << 8) | ((y >> 2) << 4) | (z >> 2);
  int sb = ((x >> 3) << 6) | ((y >> 3) << 3) | (z >> 3);
  int w  = ((x + 4) >> 3) * 81 + ((y + 4) >> 3) * 9 + ((z + 4) >> 3);
  int ib = ((x & 3) << 4) | ((y & 3) << 2) | (z & 3);
  bid[n] = b; sbid[n] = sb; wid[n] = w; ibid[n] = ib;
  atomicAdd(&cnt[b], 1);
  atomicAdd(&selcnt[sb], 1);
  atomicAdd(&wincnt[w], 1);
}

// =========================================================================
// single-block scans: occupied-block compaction + bucket offsets
// =========================================================================
__global__ __launch_bounds__(1024) void scan_all(
    const int* __restrict__ cnt, int* __restrict__ occ_m, int* __restrict__ inv,
    int* __restrict__ noccPtr,
    const int* __restrict__ selcnt, int* __restrict__ seloff, int* __restrict__ selpos,
    const int* __restrict__ wincnt, int* __restrict__ winoff, int* __restrict__ winpos) {
  __shared__ int buf[1024];
  int t = threadIdx.x;

  // ---- phase 1: compaction scan over MBLK=4096 (4 per thread) ----
  int base = t * 4;
  int f0 = cnt[base + 0] > 0, f1 = cnt[base + 1] > 0,
      f2 = cnt[base + 2] > 0, f3 = cnt[base + 3] > 0;
  int s = f0 + f1 + f2 + f3;
  buf[t] = s;
  __syncthreads();
  for (int off = 1; off < 1024; off <<= 1) {
    int add = (t >= off) ? buf[t - off] : 0;
    __syncthreads();
    buf[t] += add;
    __syncthreads();
  }
  int pos = buf[t] - s;
  if (f0) { occ_m[pos] = base + 0; inv[base + 0] = pos; pos++; }
  if (f1) { occ_m[pos] = base + 1; inv[base + 1] = pos; pos++; }
  if (f2) { occ_m[pos] = base + 2; inv[base + 2] = pos; pos++; }
  if (f3) { occ_m[pos] = base + 3; inv[base + 3] = pos; pos++; }
  if (t == 1023) noccPtr[0] = buf[1023];
  __syncthreads();

  // ---- phase 2: selection buckets (512) ----
  int v = (t < SBLK) ? selcnt[t] : 0;
  buf[t] = v;
  __syncthreads();
  for (int off = 1; off < 1024; off <<= 1) {
    int add = (t >= off) ? buf[t - off] : 0;
    __syncthreads();
    buf[t] += add;
    __syncthreads();
  }
  if (t < SBLK) {
    seloff[t + 1] = buf[t];
    selpos[t] = buf[t] - v;
    if (t == 0) seloff[0] = 0;
  }
  __syncthreads();

  // ---- phase 3: window buckets (729) ----
  int v2 = (t < NW3) ? wincnt[t] : 0;
  buf[t] = v2;
  __syncthreads();
  for (int off = 1; off < 1024; off <<= 1) {
    int add = (t >= off) ? buf[t - off] : 0;
    __syncthreads();
    buf[t] += add;
    __syncthreads();
  }
  if (t < NW3) {
    winoff[t + 1] = buf[t];
    winpos[t] = buf[t] - v2;
    if (t == 0) winoff[0] = 0;
  }
}

// =========================================================================
// scatter tokens into buckets
// =========================================================================
__global__ __launch_bounds__(256) void scatter(
    const int* __restrict__ sbid, const int* __restrict__ wid,
    int* __restrict__ selpos, int* __restrict__ winpos,
    int* __restrict__ sellist, int* __restrict__ winlist) {
  int n = blockIdx.x * 256 + threadIdx.x;
  if (n >= NT) return;
  int p = atomicAdd(&selpos[sbid[n]], 1);
  sellist[p] = n;
  int p2 = atomicAdd(&winpos[wid[n]], 1);
  winlist[p2] = n;
}

// =========================================================================
// f32 GEMM body: C[rows,512] = A[rows,512] @ B[512,512] (64x64 tile)
// kk-major LDS: inner loop = 2x ds_read_b128 per 16 FMAs.
// =========================================================================
__device__ __forceinline__ void gemm_body(
    const float* __restrict__ A, const float* __restrict__ B,
    float* __restrict__ C, int nrows) {
  int rb = blockIdx.x, cb = blockIdx.y;
  int row0 = rb * 64, col0 = cb * 64;
  if (row0 >= nrows) return;
  __shared__ float As[16][68];   // [kk][row]
  __shared__ float Bs[16][68];   // [kk][col]
  int t = threadIdx.x;
  int tx = t & 15, ty = t >> 4;
  float acc[4][4] = {};
  for (int k0 = 0; k0 < 512; k0 += 16) {
    {
      int idx = t * 4; int r = idx >> 4; int kk = idx & 15;
      int gr = row0 + r;
      float4 va = (gr < nrows) ? *(const float4*)(A + (size_t)gr * 512 + k0 + kk)
                               : make_float4(0.f, 0.f, 0.f, 0.f);
      As[kk + 0][r] = va.x; As[kk + 1][r] = va.y;
      As[kk + 2][r] = va.z; As[kk + 3][r] = va.w;
    }
    {
      int idx = t * 4; int kk = idx >> 6; int cc = idx & 63;
      float4 vb = *(const float4*)(B + (size_t)(k0 + kk) * 512 + col0 + cc);
      *(float4*)(&Bs[kk][cc]) = vb;
    }
    __syncthreads();
#pragma unroll
    for (int kk = 0; kk < 16; ++kk) {
      float4 af = *(const float4*)(&As[kk][ty * 4]);
      float4 bf = *(const float4*)(&Bs[kk][tx * 4]);
      acc[0][0] += af.x * bf.x; acc[0][1] += af.x * bf.y; acc[0][2] += af.x * bf.z; acc[0][3] += af.x * bf.w;
      acc[1][0] += af.y * bf.x; acc[1][1] += af.y * bf.y; acc[1][2] += af.y * bf.z; acc[1][3] += af.y * bf.w;
      acc[2][0] += af.z * bf.x; acc[2][1] += af.z * bf.y; acc[2][2] += af.z * bf.z; acc[2][3] += af.z * bf.w;
      acc[3][0] += af.w * bf.x; acc[3][1] += af.w * bf.y; acc[3][2] += af.w * bf.z; acc[3][3] += af.w * bf.w;
    }
    __syncthreads();
  }
#pragma unroll
  for (int i = 0; i < 4; ++i) {
    int r = row0 + ty * 4 + i;
    if (r < nrows) {
#pragma unroll
      for (int j = 0; j < 4; ++j)
        C[(size_t)r * 512 + col0 + tx * 4 + j] = acc[i][j];
    }
  }
}

__global__ __launch_bounds__(256) void gemm512(
    const float* __restrict__ A, const float* __restrict__ B, float* __restrict__ C,
    int nrowsConst) {
  gemm_body(A, B, C, nrowsConst);
}

// batched: shared A, 3 B/C pairs selected by blockIdx.z (q/k/v projections)
__global__ __launch_bounds__(256) void gemm512_b3(
    const float* __restrict__ A,
    const float* __restrict__ B0, const float* __restrict__ B1, const float* __restrict__ B2,
    float* __restrict__ C0, float* __restrict__ C1, float* __restrict__ C2) {
  const float* B = blockIdx.z == 0 ? B0 : (blockIdx.z == 1 ? B1 : B2);
  float* C = blockIdx.z == 0 ? C0 : (blockIdx.z == 1 ? C1 : C2);
  gemm_body(A, B, C, NT);
}

// batched: 2 independent GEMMs (ck/cv projections), rows from device count
__global__ __launch_bounds__(256) void gemm512_b2(
    const float* __restrict__ A0, const float* __restrict__ A1,
    const float* __restrict__ B0, const float* __restrict__ B1,
    float* __restrict__ C0, float* __restrict__ C1,
    const int* __restrict__ nrowsPtr) {
  const float* A = blockIdx.z == 0 ? A0 : A1;
  const float* B = blockIdx.z == 0 ? B0 : B1;
  float* C = blockIdx.z == 0 ? C0 : C1;
  gemm_body(A, B, C, *nrowsPtr);
}

// =========================================================================
// gate: sigmoid(feats @ Wg)   Wg:[512,3]
// =========================================================================
__global__ __launch_bounds__(256) void gatek(
    const float* __restrict__ feats, const float* __restrict__ Wg,
    float* __restrict__ gates) {
  int idx = blockIdx.x * 256 + threadIdx.x;
  if (idx >= NT * 3) return;
  int n = idx / 3, g = idx % 3;
  const float* fp = feats + (size_t)n * 512;
  float s = 0.f;
  for (int i = 0; i < 512; ++i) s += fp[i] * Wg[i * 3 + g];
  gates[idx] = 1.f / (1.f + __expf(-s));
}

// =========================================================================
// segment accumulation into compacted block means (pre-division)
// =========================================================================
__global__ __launch_bounds__(256) void accum(
    const float* __restrict__ kf, const float* __restrict__ vf,
    const float* __restrict__ pe, const int* __restrict__ bid,
    const int* __restrict__ ibid, const int* __restrict__ inv,
    float* __restrict__ ksum, float* __restrict__ vsum) {
  int n = blockIdx.x;
  int t = threadIdx.x;
  int i = inv[bid[n]];
  const float* kp = kf + (size_t)n * 512;
  const float* vp = vf + (size_t)n * 512;
  const float* pp = pe + (size_t)ibid[n] * 512;
  float* kd = ksum + (size_t)i * 512;
  float* vd = vsum + (size_t)i * 512;
  atomicAdd(&kd[t], kp[t] + pp[t]);
  atomicAdd(&kd[t + 256], kp[t + 256] + pp[t + 256]);
  atomicAdd(&vd[t], vp[t]);
  atomicAdd(&vd[t + 256], vp[t + 256]);
}

__global__ __launch_bounds__(256) void divide_means(
    float* __restrict__ ksum, float* __restrict__ vsum,
    const int* __restrict__ occ_m, const int* __restrict__ cnt,
    const int* __restrict__ noccPtr, int* __restrict__ sid_key) {
  int idx = blockIdx.x * 256 + threadIdx.x;
  int i = idx >> 9;
  if (i >= *noccPtr) return;
  float rinv = 1.f / (float)cnt[occ_m[i]];
  ksum[idx] *= rinv;
  vsum[idx] *= rinv;
  if ((idx & 511) == 0) {
    int mm2 = occ_m[i];
    sid_key[i] = (((mm2 >> 9) & 7) << 6) | (((mm2 >> 5) & 7) << 3) | ((mm2 >> 1) & 7);
  }
}

// =========================================================================
// transpose compressed keys into ckT4: [dgroup=d/4][key (KPAD stride)][4]
// (float4-loadable per key)
// =========================================================================
__global__ __launch_bounds__(256) void transp(
    const float* __restrict__ src, float* __restrict__ dst,
    const int* __restrict__ noccPtr) {
  __shared__ float tile[64][65];
  int nocc = *noccPtr;
  int k0 = blockIdx.x * 64;   // key tile
  int d0 = blockIdx.y * 64;   // dim tile
  int c = threadIdx.x & 63, r0 = (threadIdx.x >> 6) * 16;
  for (int r = 0; r < 16; ++r) {
    int key = k0 + r0 + r;
    tile[r0 + r][c] = (key < nocc) ? src[(size_t)key * 512 + d0 + c] : 0.f;
  }
  __syncthreads();
  // lane c = key; write 4 dim-groups of this 64-dim tile
  float4* dst4 = (float4*)dst;
  int gl0 = (threadIdx.x >> 6) * 4;
#pragma unroll
  for (int gg = 0; gg < 4; ++gg) {
    int gl = gl0 + gg;                   // local dim-group 0..15
    float4 v = make_float4(tile[c][gl * 4 + 0], tile[c][gl * 4 + 1],
                           tile[c][gl * 4 + 2], tile[c][gl * 4 + 3]);
    dst4[(size_t)(d0 / 4 + gl) * KPAD + k0 + c] = v;
  }
}

// =========================================================================
// cattn merged kernel (cqkpv) v3: 4 tokens/block, 2-key register blocking,
// float4 ck loads, QK c-loop unroll LIMITED to 4 — R12's spill (VGPR 128,
// GBs of scratch) was caused by full unroll hoisting all 32 dwordx4 loads
// (128 VGPRs in flight). unroll 4 caps in-flight loads at 8 (32 regs).
// grid (512 groups, 4 quarters), 512 thr = 8 waves = 8 heads.
// =========================================================================
__global__ __launch_bounds__(512) void cqkpv(
    const float* __restrict__ q, const float* __restrict__ ckT4,
    const float* __restrict__ cv, const int* __restrict__ noccPtr,
    float* __restrict__ S, float* __restrict__ lpart,
    float* __restrict__ opart) {
  __shared__ float qlds[4 * 512];       // 8 KB (tok-major)
  __shared__ float pmat[8][4][128];     // 16 KB
  __shared__ float lred[8][4];
  const int g = blockIdx.x;             // 4-token group
  const int n0 = g * 4;
  const int quarter = blockIdx.y;
  const int t = threadIdx.x;
  const int nocc = *noccPtr;
  const int qbeg = (nocc * quarter) >> 2;
  const int qend = (nocc * (quarter + 1)) >> 2;
  const int l = t & 63;
  const int h = __builtin_amdgcn_readfirstlane(t >> 6);

  for (int idx = t; idx < 2048; idx += 512)
    qlds[idx] = q[(size_t)n0 * 512 + idx];
  __syncthreads();

  const float4* ckp = (const float4*)ckT4 + (size_t)(h * 16) * KPAD;
  const float* qh = qlds + h * 64;      // + tok*512 + d
  // S row layout identical to R11 (8-token groups): row = (n>>3)*64 + h*8 + (n&7)
  float* Srow = S + ((size_t)(g >> 1) * 64 + h * 8 + (g & 1) * 4) * KPAD;

  float lacc[4] = {0.f, 0.f, 0.f, 0.f};
  float o[4]    = {0.f, 0.f, 0.f, 0.f};

  for (int i0 = qbeg; i0 < qend; i0 += 128) {
    int lim = qend - i0; lim = lim > 128 ? 128 : lim;
    int ia = i0 + l;
    int ibRaw = ia + 64;
    bool va = ia < qend, vb = ibRaw < qend;
    int iA = va ? ia : (qend - 1);
    int iB = vb ? ibRaw : iA;
    float sa[4] = {0.f, 0.f, 0.f, 0.f};
    float sb[4] = {0.f, 0.f, 0.f, 0.f};
#pragma unroll 4
    for (int c = 0; c < 16; ++c) {
      float4 ka = ckp[(size_t)c * KPAD + iA];
      float4 kb = ckp[(size_t)c * KPAD + iB];
#pragma unroll
      for (int tok = 0; tok < 4; ++tok) {
        float4 qv = *(const float4*)(qh + tok * 512 + c * 4);
        sa[tok] += ka.x * qv.x + ka.y * qv.y + ka.z * qv.z + ka.w * qv.w;
        sb[tok] += kb.x * qv.x + kb.y * qv.y + kb.z * qv.z + kb.w * qv.w;
      }
    }
    float pa[4], pb[4];
#pragma unroll
    for (int tok = 0; tok < 4; ++tok) {
      pa[tok] = va ? __expf(sa[tok] * 0.125f) : 0.f;
      pb[tok] = vb ? __expf(sb[tok] * 0.125f) : 0.f;
      lacc[tok] += pa[tok] + pb[tok];
      if (va) Srow[(size_t)tok * KPAD + ia] = pa[tok];
      if (vb) Srow[(size_t)tok * KPAD + ibRaw] = pb[tok];
    }
    __syncthreads();   // prior tile's pmat fully consumed
#pragma unroll
    for (int tok = 0; tok < 4; ++tok) {
      pmat[h][tok][l] = pa[tok];
      pmat[h][tok][64 + l] = pb[tok];
    }
    __syncthreads();
    // PV (unnormalized): lane = output dim; wave covers all keys of the tile
    {
      const float* cvp = cv + (size_t)i0 * 512 + h * 64 + l;
      int g4 = lim >> 2;
      for (int gg = 0; gg < g4; ++gg) {
        float v0 = cvp[(size_t)(gg * 4 + 0) * 512];
        float v1 = cvp[(size_t)(gg * 4 + 1) * 512];
        float v2 = cvp[(size_t)(gg * 4 + 2) * 512];
        float v3 = cvp[(size_t)(gg * 4 + 3) * 512];
#pragma unroll
        for (int tok = 0; tok < 4; ++tok) {
          float4 pm = *(const float4*)(&pmat[h][tok][gg * 4]);
          o[tok] += pm.x * v0 + pm.y * v1 + pm.z * v2 + pm.w * v3;
        }
      }
      for (int j = g4 * 4; j < lim; ++j) {
        float v = cvp[(size_t)j * 512];
#pragma unroll
        for (int tok = 0; tok < 4; ++tok) o[tok] += pmat[h][tok][j] * v;
      }
    }
  }

  // l partial reduce across lanes -> lpart[quarter][n][h]
#pragma unroll
  for (int tok = 0; tok < 4; ++tok) {
    float l2 = lacc[tok];
#pragma unroll
    for (int s2 = 32; s2; s2 >>= 1) l2 += __shfl_xor(l2, s2, 64);
    if (l == 0) lred[h][tok] = l2;
  }
  __syncthreads();
  if (t < 32) {
    int h2 = t & 7, tok = t >> 3;
    lpart[((size_t)quarter * NT + n0 + tok) * 8 + h2] = lred[h2][tok];
  }
  // per-quarter unnormalized o partial
#pragma unroll
  for (int tok = 0; tok < 4; ++tok)
    opart[((size_t)quarter * NT + n0 + tok) * 512 + h * 64 + l] = o[tok];
}

// =========================================================================
// cselfin: per 8-token group. rl = 1/l_tot, pools heads over S, segment-sums
// selection scores (LDS atomics), top-8, fused = gate0 * o_un / l.
// =========================================================================
__global__ __launch_bounds__(256) void cselfin(
    const float* __restrict__ S, const float* __restrict__ lpart,
    const float* __restrict__ opart, const int* __restrict__ sid_key,
    const int* __restrict__ noccPtr, const float* __restrict__ gates,
    float* __restrict__ fused, int* __restrict__ topk_out) {
  __shared__ float selsc[8 * 512];   // 16 KB
  __shared__ float rlh[8][8];        // [tok][h]
  const int bx = blockIdx.x, t = threadIdx.x;
  const int n0 = bx * 8;
  const int nocc = *noccPtr;

  for (int idx = t; idx < 4096; idx += 256) selsc[idx] = 0.f;
  if (t < 64) {
    int tok = t >> 3, h = t & 7;
    float lt = 0.f;
#pragma unroll
    for (int qq = 0; qq < 4; ++qq)
      lt += lpart[((size_t)qq * NT + n0 + tok) * 8 + h];
    rlh[tok][h] = 1.f / lt;
  }
  __syncthreads();

  const float* Sb = S + (size_t)bx * 64 * KPAD;   // rows (h*8 + tok)
  for (int tok = 0; tok < 8; ++tok) {
    for (int i0 = 0; i0 < nocc; i0 += 256) {
      int i = i0 + t;
      if (i < nocc) {
        float ps = 0.f;
#pragma unroll
        for (int h = 0; h < 8; ++h)
          ps += Sb[((size_t)h * 8 + tok) * KPAD + i] * rlh[tok][h];
        atomicAdd(&selsc[tok * 512 + sid_key[i]], ps);
      }
    }
  }
  __syncthreads();

  // fused = gate0 * (sum_q o_un) / l_tot
  for (int idx = t; idx < 4096; idx += 256) {
    int tok = idx >> 9, d = idx & 511, h = d >> 6;
    float osum = 0.f;
#pragma unroll
    for (int qq = 0; qq < 4; ++qq)
      osum += opart[((size_t)qq * NT + n0 + tok) * 512 + d];
    fused[(size_t)(n0 + tok) * 512 + d] = gates[(n0 + tok) * 3] * osum * rlh[tok][h];
  }

  // top-8 per token: 4 waves x 2 tokens (value desc, index asc ties)
  int w = t >> 6, l = t & 63;
  for (int tk2 = 0; tk2 < 2; ++tk2) {
    int tok = w * 2 + tk2;
    float* sp = selsc + tok * 512;
    float v[8];
#pragma unroll
    for (int r = 0; r < 8; ++r) v[r] = sp[r * 64 + l];
#pragma unroll
    for (int k = 0; k < 8; ++k) {
      float bv = v[0]; int bi = l;
#pragma unroll
      for (int r = 1; r < 8; ++r)
        if (v[r] > bv) { bv = v[r]; bi = r * 64 + l; }
#pragma unroll
      for (int s2 = 32; s2; s2 >>= 1) {
        float ov = __shfl_xor(bv, s2, 64);
        int oi = __shfl_xor(bi, s2, 64);
        if (ov > bv || (ov == bv && oi < bi)) { bv = ov; bi = oi; }
      }
      if (l == 0) topk_out[(n0 + tok) * 8 + k] = bi;
#pragma unroll
      for (int r = 0; r < 8; ++r)
        if (bi == r * 64 + l) v[r] = NEGI;
    }
  }
}

// =========================================================================
// selection + window attention (sparse, bucketed), adds into fused
// =========================================================================
__global__ __launch_bounds__(64) void selwin(
    const float* __restrict__ q, const float* __restrict__ kf,
    const float* __restrict__ vf, const int* __restrict__ topk,
    const int* __restrict__ seloff, const int* __restrict__ sellist,
    const int* __restrict__ winoff, const int* __restrict__ winlist,
    const int* __restrict__ wid_tok, const float* __restrict__ gates,
    float* __restrict__ fused) {
  int n = blockIdx.x, t = threadIdx.x;
  int h = t >> 3, j = t & 7;
  float q8[8];
  const float* qp = q + (size_t)n * 512 + h * 64 + j * 8;
#pragma unroll
  for (int d = 0; d < 8; ++d) q8[d] = qp[d];

  // ---- selection branch ----
  float os[8];
#pragma unroll
  for (int d = 0; d < 8; ++d) os[d] = 0.f;
  float m = NEGI, lsum = 0.f;
  for (int k = 0; k < 8; ++k) {
    int s = topk[n * 8 + k];
    int e0 = seloff[s], e1 = seloff[s + 1];
    for (int idx = e0; idx < e1; ++idx) {
      int tj = sellist[idx];
      const float* kp = kf + (size_t)tj * 512 + h * 64 + j * 8;
      float part = 0.f;
#pragma unroll
      for (int d = 0; d < 8; ++d) part += q8[d] * kp[d];
      part += __shfl_xor(part, 1, 64);
      part += __shfl_xor(part, 2, 64);
      part += __shfl_xor(part, 4, 64);
      float sc = part * 0.125f;
      float nm = fmaxf(m, sc);
      float scale = __expf(m - nm);
      float pv = __expf(sc - nm);
      const float* vp = vf + (size_t)tj * 512 + h * 64 + j * 8;
      lsum = lsum * scale + pv;
#pragma unroll
      for (int d = 0; d < 8; ++d) os[d] = os[d] * scale + pv * vp[d];
      m = nm;
    }
  }
  {
    float rl = (lsum > 0.f) ? 1.f / lsum : 0.f;
#pragma unroll
    for (int d = 0; d < 8; ++d) os[d] *= rl;
  }

  // ---- window branch ----
  float ow[8];
#pragma unroll
  for (int d = 0; d < 8; ++d) ow[d] = 0.f;
  m = NEGI; lsum = 0.f;
  int w = wid_tok[n];
  int e0 = winoff[w], e1 = winoff[w + 1];
  for (int idx = e0; idx < e1; ++idx) {
    int tj = winlist[idx];
    const float* kp = kf + (size_t)tj * 512 + h * 64 + j * 8;
    float part = 0.f;
#pragma unroll
    for (int d = 0; d < 8; ++d) part += q8[d] * kp[d];
    part += __shfl_xor(part, 1, 64);
    part += __shfl_xor(part, 2, 64);
    part += __shfl_xor(part, 4, 64);
    float sc = part * 0.125f;
    float nm = fmaxf(m, sc);
    float scale = __expf(m - nm);
    float pv = __expf(sc - nm);
    const float* vp = vf + (size_t)tj * 512 + h * 64 + j * 8;
    lsum = lsum * scale + pv;
#pragma unroll
    for (int d = 0; d < 8; ++d) ow[d] = ow[d] * scale + pv * vp[d];
    m = nm;
  }
  {
    float rl = (lsum > 0.f) ? 1.f / lsum : 0.f;
#pragma unroll
    for (int d = 0; d < 8; ++d) ow[d] *= rl;
  }

  float g1 = gates[n * 3 + 1], g2 = gates[n * 3 + 2];
  float* fp = fused + (size_t)n * 512 + h * 64 + j * 8;
#pragma unroll
  for (int d = 0; d < 8; ++d) fp[d] += g1 * os[d] + g2 * ow[d];
}

// =========================================================================
// launcher
// =========================================================================
extern "C" void kernel_launch(void* const* d_in, const int* in_sizes, int n_in,
                              void* d_out, int out_size, void* d_ws, size_t ws_size,
                              hipStream_t stream) {
  const float* feats = (const float*)d_in[0];
  const int* coords  = (const int*)d_in[1];
  const float* Wq  = (const float*)d_in[2];
  const float* Wk  = (const float*)d_in[3];
  const float* Wv  = (const float*)d_in[4];
  const float* Wo  = (const float*)d_in[5];
  const float* Wck = (const float*)d_in[6];
  const float* Wcv = (const float*)d_in[7];
  const float* pe  = (const float*)d_in[8];
  const float* Wg  = (const float*)d_in[9];
  float* out = (float*)d_out;

  char* p = (char*)d_ws;
  auto alloc = [&](size_t bytes) -> char* {
    char* r = p;
    p += (bytes + 255) & ~(size_t)255;
    return r;
  };
  float* q     = (float*)alloc((size_t)NT * 512 * 4);
  float* kf    = (float*)alloc((size_t)NT * 512 * 4);
  float* vf    = (float*)alloc((size_t)NT * 512 * 4);
  float* fused = (float*)alloc((size_t)NT * 512 * 4);
  float* zf    = (float*)alloc((size_t)2 * NT * 512 * 4);  // ckbar|cvbar (zeroed)
  float* ckbar = zf;
  float* cvbar = zf + (size_t)NT * 512;
  float* ckc   = (float*)alloc((size_t)NT * 512 * 4);
  float* cvc   = (float*)alloc((size_t)NT * 512 * 4);
  float* ckT   = (float*)alloc((size_t)512 * KPAD * 4);
  float* gates = (float*)alloc((size_t)NT * 3 * 4);
  float* lpart = (float*)alloc((size_t)4 * NT * 8 * 4);
  float* opart = (float*)alloc((size_t)4 * NT * 512 * 4);
  int* zi      = (int*)alloc((size_t)(MBLK + SBLK + NW3) * 4);  // cnt|selcnt|wincnt
  int* cnt = zi;
  int* selcnt = zi + MBLK;
  int* wincnt = zi + MBLK + SBLK;
  int* inv     = (int*)alloc((size_t)MBLK * 4);
  int* occ     = (int*)alloc((size_t)NT * 4);
  int* nocc    = (int*)alloc(4);
  int* bid     = (int*)alloc((size_t)NT * 4);
  int* sbid    = (int*)alloc((size_t)NT * 4);
  int* wid     = (int*)alloc((size_t)NT * 4);
  int* ibid    = (int*)alloc((size_t)NT * 4);
  int* sid_key = (int*)alloc((size_t)NT * 4);
  int* seloff  = (int*)alloc((size_t)(SBLK + 1) * 4);
  int* selpos  = (int*)alloc((size_t)SBLK * 4);
  int* sellist = (int*)alloc((size_t)NT * 4);
  int* winoff  = (int*)alloc((size_t)(NW3 + 1) * 4);
  int* winpos  = (int*)alloc((size_t)NW3 * 4);
  int* winlist = (int*)alloc((size_t)NT * 4);
  int* topk    = (int*)alloc((size_t)NT * 8 * 4);
  // big S buffer last: 256 groups x 64 rows x KPAD f32 = 128 MB
  size_t sbytes = (size_t)(NT / 8) * 64 * KPAD * 4;
  float* S = (float*)alloc(sbytes);

  hipMemsetAsync(zf, 0, (size_t)2 * NT * 512 * 4, stream);
  hipMemsetAsync(zi, 0, (size_t)(MBLK + SBLK + NW3) * 4, stream);

  token_prep<<<8, 256, 0, stream>>>(coords, bid, sbid, wid, ibid, cnt, selcnt, wincnt);
  scan_all<<<1, 1024, 0, stream>>>(cnt, occ, inv, nocc, selcnt, seloff, selpos,
                                   wincnt, winoff, winpos);
  scatter<<<8, 256, 0, stream>>>(sbid, wid, selpos, winpos, sellist, winlist);

  gemm512_b3<<<dim3(32, 8, 3), 256, 0, stream>>>(feats, Wq, Wk, Wv, q, kf, vf);
  gatek<<<24, 256, 0, stream>>>(feats, Wg, gates);

  accum<<<NT, 256, 0, stream>>>(kf, vf, pe, bid, ibid, inv, ckbar, cvbar);
  divide_means<<<4096, 256, 0, stream>>>(ckbar, cvbar, occ, cnt, nocc, sid_key);
  gemm512_b2<<<dim3(32, 8, 2), 256, 0, stream>>>(ckbar, cvbar, Wck, Wcv, ckc, cvc, nocc);
  transp<<<dim3(32, 8), 256, 0, stream>>>(ckc, ckT, nocc);

  cqkpv<<<dim3(512, 4), 512, 0, stream>>>(q, ckT, cvc, nocc, S, lpart, opart);
  cselfin<<<256, 256, 0, stream>>>(S, lpart, opart, sid_key, nocc, gates,
                                   fused, topk);

  selwin<<<NT, 64, 0, stream>>>(q, kf, vf, topk, seloff, sellist, winoff, winlist,
                                wid, gates, fused);
  gemm512<<<dim3(32, 8), 256, 0, stream>>>(fused, Wo, out, NT);
}

// Round 14
// 441.221 us; speedup vs baseline: 3.5355x; 1.5101x over previous
//
#include <hip/hip_runtime.h>

// ---- problem constants ----
constexpr int NT   = 2048;   // tokens
constexpr int HD   = 512;    // hidden = HQ*D = HKV*D
constexpr int MBLK = 4096;   // 16^3 compression block slots
constexpr int SBLK = 512;    // 8^3 selection block slots
constexpr int NW3  = 729;    // 9^3 shifted windows
constexpr int KPAD = 2048;   // padded key stride for ckT / S rows
#define NEGI (-1e30f)

// =========================================================================
// token prep: coords decode, ids, bucket counts
// =========================================================================
__global__ __launch_bounds__(256) void token_prep(
    const int* __restrict__ cf, int* __restrict__ bid, int* __restrict__ sbid,
    int* __restrict__ wid, int* __restrict__ ibid, int* __restrict__ cnt,
    int* __restrict__ selcnt, int* __restrict__ wincnt) {
  int n = blockIdx.x * 256 + threadIdx.x;
  if (n >= NT) return;
  int c = cf[n];
  int x = c >> 12, y = (c >> 6) & 63, z = c & 63;
  int b  = ((x >> 2) << 8) | ((y >> 2) << 4) | (z >> 2);
  int sb = ((x >> 3) << 6) | ((y >> 3) << 3) | (z >> 3);
  int w  = ((x + 4) >> 3) * 81 + ((y + 4) >> 3) * 9 + ((z + 4) >> 3);
  int ib = ((x & 3) << 4) | ((y & 3) << 2) | (z & 3);
  bid[n] = b; sbid[n] = sb; wid[n] = w; ibid[n] = ib;
  atomicAdd(&cnt[b], 1);
  atomicAdd(&selcnt[sb], 1);
  atomicAdd(&wincnt[w], 1);
}

// =========================================================================
// single-block scans: occupied-block compaction + bucket offsets
// =========================================================================
__global__ __launch_bounds__(1024) void scan_all(
    const int* __restrict__ cnt, int* __restrict__ occ_m, int* __restrict__ inv,
    int* __restrict__ noccPtr,
    const int* __restrict__ selcnt, int* __restrict__ seloff, int* __restrict__ selpos,
    const int* __restrict__ wincnt, int* __restrict__ winoff, int* __restrict__ winpos) {
  __shared__ int buf[1024];
  int t = threadIdx.x;

  // ---- phase 1: compaction scan over MBLK=4096 (4 per thread) ----
  int base = t * 4;
  int f0 = cnt[base + 0] > 0, f1 = cnt[base + 1] > 0,
      f2 = cnt[base + 2] > 0, f3 = cnt[base + 3] > 0;
  int s = f0 + f1 + f2 + f3;
  buf[t] = s;
  __syncthreads();
  for (int off = 1; off < 1024; off <<= 1) {
    int add = (t >= off) ? buf[t - off] : 0;
    __syncthreads();
    buf[t] += add;
    __syncthreads();
  }
  int pos = buf[t] - s;
  if (f0) { occ_m[pos] = base + 0; inv[base + 0] = pos; pos++; }
  if (f1) { occ_m[pos] = base + 1; inv[base + 1] = pos; pos++; }
  if (f2) { occ_m[pos] = base + 2; inv[base + 2] = pos; pos++; }
  if (f3) { occ_m[pos] = base + 3; inv[base + 3] = pos; pos++; }
  if (t == 1023) noccPtr[0] = buf[1023];
  __syncthreads();

  // ---- phase 2: selection buckets (512) ----
  int v = (t < SBLK) ? selcnt[t] : 0;
  buf[t] = v;
  __syncthreads();
  for (int off = 1; off < 1024; off <<= 1) {
    int add = (t >= off) ? buf[t - off] : 0;
    __syncthreads();
    buf[t] += add;
    __syncthreads();
  }
  if (t < SBLK) {
    seloff[t + 1] = buf[t];
    selpos[t] = buf[t] - v;
    if (t == 0) seloff[0] = 0;
  }
  __syncthreads();

  // ---- phase 3: window buckets (729) ----
  int v2 = (t < NW3) ? wincnt[t] : 0;
  buf[t] = v2;
  __syncthreads();
  for (int off = 1; off < 1024; off <<= 1) {
    int add = (t >= off) ? buf[t - off] : 0;
    __syncthreads();
    buf[t] += add;
    __syncthreads();
  }
  if (t < NW3) {
    winoff[t + 1] = buf[t];
    winpos[t] = buf[t] - v2;
    if (t == 0) winoff[0] = 0;
  }
}

// =========================================================================
// scatter tokens into buckets
// =========================================================================
__global__ __launch_bounds__(256) void scatter(
    const int* __restrict__ sbid, const int* __restrict__ wid,
    int* __restrict__ selpos, int* __restrict__ winpos,
    int* __restrict__ sellist, int* __restrict__ winlist) {
  int n = blockIdx.x * 256 + threadIdx.x;
  if (n >= NT) return;
  int p = atomicAdd(&selpos[sbid[n]], 1);
  sellist[p] = n;
  int p2 = atomicAdd(&winpos[wid[n]], 1);
  winlist[p2] = n;
}

// =========================================================================
// f32 GEMM body: C[rows,512] = A[rows,512] @ B[512,512] (64x64 tile)
// kk-major LDS: inner loop = 2x ds_read_b128 per 16 FMAs.
// =========================================================================
__device__ __forceinline__ void gemm_body(
    const float* __restrict__ A, const float* __restrict__ B,
    float* __restrict__ C, int nrows) {
  int rb = blockIdx.x, cb = blockIdx.y;
  int row0 = rb * 64, col0 = cb * 64;
  if (row0 >= nrows) return;
  __shared__ float As[16][68];   // [kk][row]
  __shared__ float Bs[16][68];   // [kk][col]
  int t = threadIdx.x;
  int tx = t & 15, ty = t >> 4;
  float acc[4][4] = {};
  for (int k0 = 0; k0 < 512; k0 += 16) {
    {
      int idx = t * 4; int r = idx >> 4; int kk = idx & 15;
      int gr = row0 + r;
      float4 va = (gr < nrows) ? *(const float4*)(A + (size_t)gr * 512 + k0 + kk)
                               : make_float4(0.f, 0.f, 0.f, 0.f);
      As[kk + 0][r] = va.x; As[kk + 1][r] = va.y;
      As[kk + 2][r] = va.z; As[kk + 3][r] = va.w;
    }
    {
      int idx = t * 4; int kk = idx >> 6; int cc = idx & 63;
      float4 vb = *(const float4*)(B + (size_t)(k0 + kk) * 512 + col0 + cc);
      *(float4*)(&Bs[kk][cc]) = vb;
    }
    __syncthreads();
#pragma unroll
    for (int kk = 0; kk < 16; ++kk) {
      float4 af = *(const float4*)(&As[kk][ty * 4]);
      float4 bf = *(const float4*)(&Bs[kk][tx * 4]);
      acc[0][0] += af.x * bf.x; acc[0][1] += af.x * bf.y; acc[0][2] += af.x * bf.z; acc[0][3] += af.x * bf.w;
      acc[1][0] += af.y * bf.x; acc[1][1] += af.y * bf.y; acc[1][2] += af.y * bf.z; acc[1][3] += af.y * bf.w;
      acc[2][0] += af.z * bf.x; acc[2][1] += af.z * bf.y; acc[2][2] += af.z * bf.z; acc[2][3] += af.z * bf.w;
      acc[3][0] += af.w * bf.x; acc[3][1] += af.w * bf.y; acc[3][2] += af.w * bf.z; acc[3][3] += af.w * bf.w;
    }
    __syncthreads();
  }
#pragma unroll
  for (int i = 0; i < 4; ++i) {
    int r = row0 + ty * 4 + i;
    if (r < nrows) {
#pragma unroll
      for (int j = 0; j < 4; ++j)
        C[(size_t)r * 512 + col0 + tx * 4 + j] = acc[i][j];
    }
  }
}

__global__ __launch_bounds__(256) void gemm512(
    const float* __restrict__ A, const float* __restrict__ B, float* __restrict__ C,
    int nrowsConst) {
  gemm_body(A, B, C, nrowsConst);
}

// batched: shared A, 3 B/C pairs selected by blockIdx.z (q/k/v projections)
__global__ __launch_bounds__(256) void gemm512_b3(
    const float* __restrict__ A,
    const float* __restrict__ B0, const float* __restrict__ B1, const float* __restrict__ B2,
    float* __restrict__ C0, float* __restrict__ C1, float* __restrict__ C2) {
  const float* B = blockIdx.z == 0 ? B0 : (blockIdx.z == 1 ? B1 : B2);
  float* C = blockIdx.z == 0 ? C0 : (blockIdx.z == 1 ? C1 : C2);
  gemm_body(A, B, C, NT);
}

// batched: 2 independent GEMMs (ck/cv projections), rows from device count
__global__ __launch_bounds__(256) void gemm512_b2(
    const float* __restrict__ A0, const float* __restrict__ A1,
    const float* __restrict__ B0, const float* __restrict__ B1,
    float* __restrict__ C0, float* __restrict__ C1,
    const int* __restrict__ nrowsPtr) {
  const float* A = blockIdx.z == 0 ? A0 : A1;
  const float* B = blockIdx.z == 0 ? B0 : B1;
  float* C = blockIdx.z == 0 ? C0 : C1;
  gemm_body(A, B, C, *nrowsPtr);
}

// =========================================================================
// gate: sigmoid(feats @ Wg)   Wg:[512,3]
// =========================================================================
__global__ __launch_bounds__(256) void gatek(
    const float* __restrict__ feats, const float* __restrict__ Wg,
    float* __restrict__ gates) {
  int idx = blockIdx.x * 256 + threadIdx.x;
  if (idx >= NT * 3) return;
  int n = idx / 3, g = idx % 3;
  const float* fp = feats + (size_t)n * 512;
  float s = 0.f;
  for (int i = 0; i < 512; ++i) s += fp[i] * Wg[i * 3 + g];
  gates[idx] = 1.f / (1.f + __expf(-s));
}

// =========================================================================
// segment accumulation into compacted block means (pre-division)
// =========================================================================
__global__ __launch_bounds__(256) void accum(
    const float* __restrict__ kf, const float* __restrict__ vf,
    const float* __restrict__ pe, const int* __restrict__ bid,
    const int* __restrict__ ibid, const int* __restrict__ inv,
    float* __restrict__ ksum, float* __restrict__ vsum) {
  int n = blockIdx.x;
  int t = threadIdx.x;
  int i = inv[bid[n]];
  const float* kp = kf + (size_t)n * 512;
  const float* vp = vf + (size_t)n * 512;
  const float* pp = pe + (size_t)ibid[n] * 512;
  float* kd = ksum + (size_t)i * 512;
  float* vd = vsum + (size_t)i * 512;
  atomicAdd(&kd[t], kp[t] + pp[t]);
  atomicAdd(&kd[t + 256], kp[t + 256] + pp[t + 256]);
  atomicAdd(&vd[t], vp[t]);
  atomicAdd(&vd[t + 256], vp[t + 256]);
}

__global__ __launch_bounds__(256) void divide_means(
    float* __restrict__ ksum, float* __restrict__ vsum,
    const int* __restrict__ occ_m, const int* __restrict__ cnt,
    const int* __restrict__ noccPtr, int* __restrict__ sid_key) {
  int idx = blockIdx.x * 256 + threadIdx.x;
  int i = idx >> 9;
  if (i >= *noccPtr) return;
  float rinv = 1.f / (float)cnt[occ_m[i]];
  ksum[idx] *= rinv;
  vsum[idx] *= rinv;
  if ((idx & 511) == 0) {
    int mm2 = occ_m[i];
    sid_key[i] = (((mm2 >> 9) & 7) << 6) | (((mm2 >> 5) & 7) << 3) | ((mm2 >> 1) & 7);
  }
}

// =========================================================================
// transpose compressed keys: ckT[d][key] (KPAD stride) from ckc[key][d]
// =========================================================================
__global__ __launch_bounds__(256) void transp(
    const float* __restrict__ src, float* __restrict__ dst,
    const int* __restrict__ noccPtr) {
  __shared__ float tile[64][65];
  int nocc = *noccPtr;
  int k0 = blockIdx.x * 64;   // key tile
  int d0 = blockIdx.y * 64;   // dim tile
  int c = threadIdx.x & 63, r0 = (threadIdx.x >> 6) * 16;
  for (int r = 0; r < 16; ++r) {
    int key = k0 + r0 + r;
    tile[r0 + r][c] = (key < nocc) ? src[(size_t)key * 512 + d0 + c] : 0.f;
  }
  __syncthreads();
  for (int r = 0; r < 16; ++r)
    dst[(size_t)(d0 + r0 + r) * KPAD + k0 + c] = tile[c][r0 + r];
}

// =========================================================================
// cattn merged kernel (cqkpv): R11-exact proven body (218 us, VGPR 64).
// QK once per (token,key); q in LDS (broadcast float4); ck scalar dwords.
// Stores e = exp(sc) to S, unnormalized PV partials per key-quarter + l.
// grid (256, 4 quarters), 512 thr = 8 waves = 8 heads; lane = key/dim.
// DO NOT restructure: 2-key blocking (R10/R12/R13) and min-waves hints
// (R6) all regressed via spills or occupancy collapse.
// =========================================================================
__global__ __launch_bounds__(512) void cqkpv(
    const float* __restrict__ q, const float* __restrict__ ckT,
    const float* __restrict__ cv, const int* __restrict__ noccPtr,
    float* __restrict__ S, float* __restrict__ lpart,
    float* __restrict__ opart) {
  __shared__ float qlds[8 * 512];       // 16 KB (tok-major: [tok][512])
  __shared__ float pmat[8][8][64];      // 16 KB
  __shared__ float lred[8][8];
  const int n0 = blockIdx.x * 8;
  const int quarter = blockIdx.y;
  const int t = threadIdx.x;
  const int nocc = *noccPtr;
  const int qbeg = (nocc * quarter) >> 2;
  const int qend = (nocc * (quarter + 1)) >> 2;
  const int l = t & 63;
  const int h = __builtin_amdgcn_readfirstlane(t >> 6);

  for (int idx = t; idx < 4096; idx += 512)
    qlds[idx] = q[(size_t)n0 * 512 + idx];
  __syncthreads();

  const float* ckTh = ckT + (size_t)h * 64 * KPAD;
  const float* qh = qlds + h * 64;      // + tok*512 + d
  float* Srow = S + (size_t)(blockIdx.x * 8 + h) * 8 * KPAD;  // + tok*KPAD + i

  float lacc[8];
  float o[8];
#pragma unroll
  for (int tok = 0; tok < 8; ++tok) { lacc[tok] = 0.f; o[tok] = 0.f; }

  for (int i0 = qbeg; i0 < qend; i0 += 64) {
    int lim = qend - i0; lim = lim > 64 ? 64 : lim;
    int i = i0 + l;
    bool valid = i < qend;
    float p[8];
    if (valid) {
      float sacc[8];
#pragma unroll
      for (int tok = 0; tok < 8; ++tok) sacc[tok] = 0.f;
#pragma unroll
      for (int c = 0; c < 16; ++c) {
        float k0 = ckTh[(size_t)(c * 4 + 0) * KPAD + i];
        float k1 = ckTh[(size_t)(c * 4 + 1) * KPAD + i];
        float k2 = ckTh[(size_t)(c * 4 + 2) * KPAD + i];
        float k3 = ckTh[(size_t)(c * 4 + 3) * KPAD + i];
#pragma unroll
        for (int tok = 0; tok < 8; ++tok) {
          float4 qv = *(const float4*)(qh + tok * 512 + c * 4);
          sacc[tok] += k0 * qv.x + k1 * qv.y + k2 * qv.z + k3 * qv.w;
        }
      }
#pragma unroll
      for (int tok = 0; tok < 8; ++tok) {
        p[tok] = __expf(sacc[tok] * 0.125f);
        lacc[tok] += p[tok];
        Srow[(size_t)tok * KPAD + i] = p[tok];
      }
    }
    __syncthreads();   // prior tile's pmat fully consumed
    if (valid) {
#pragma unroll
      for (int tok = 0; tok < 8; ++tok) pmat[h][tok][l] = p[tok];
    }
    __syncthreads();
    // PV (unnormalized): lane = output dim; wave covers all keys of the tile
    {
      const float* cvp = cv + (size_t)i0 * 512 + h * 64 + l;
      int g4 = lim >> 2;
      for (int g = 0; g < g4; ++g) {
        float v0 = cvp[(size_t)(g * 4 + 0) * 512];
        float v1 = cvp[(size_t)(g * 4 + 1) * 512];
        float v2 = cvp[(size_t)(g * 4 + 2) * 512];
        float v3 = cvp[(size_t)(g * 4 + 3) * 512];
#pragma unroll
        for (int tok = 0; tok < 8; ++tok) {
          float4 pm = *(const float4*)(&pmat[h][tok][g * 4]);
          o[tok] += pm.x * v0 + pm.y * v1 + pm.z * v2 + pm.w * v3;
        }
      }
      for (int j = g4 * 4; j < lim; ++j) {
        float v = cvp[(size_t)j * 512];
#pragma unroll
        for (int tok = 0; tok < 8; ++tok) o[tok] += pmat[h][tok][j] * v;
      }
    }
  }

  // l partial reduce across lanes -> lpart[quarter][n][h]
#pragma unroll
  for (int tok = 0; tok < 8; ++tok) {
    float l2 = lacc[tok];
#pragma unroll
    for (int s2 = 32; s2; s2 >>= 1) l2 += __shfl_xor(l2, s2, 64);
    if (l == 0) lred[h][tok] = l2;
  }
  __syncthreads();
  if (t < 64) {
    int h2 = t & 7, tok = t >> 3;
    lpart[((size_t)quarter * NT + n0 + tok) * 8 + h2] = lred[h2][tok];
  }
  // per-quarter unnormalized o partial
#pragma unroll
  for (int tok = 0; tok < 8; ++tok)
    opart[((size_t)quarter * NT + n0 + tok) * 512 + h * 64 + l] = o[tok];
}

// =========================================================================
// cselfin: per 8-token group. rl = 1/l_tot, pools heads over S, segment-sums
// selection scores (LDS atomics), top-8, fused = gate0 * o_un / l.
// =========================================================================
__global__ __launch_bounds__(256) void cselfin(
    const float* __restrict__ S, const float* __restrict__ lpart,
    const float* __restrict__ opart, const int* __restrict__ sid_key,
    const int* __restrict__ noccPtr, const float* __restrict__ gates,
    float* __restrict__ fused, int* __restrict__ topk_out) {
  __shared__ float selsc[8 * 512];   // 16 KB
  __shared__ float rlh[8][8];        // [tok][h]
  const int bx = blockIdx.x, t = threadIdx.x;
  const int n0 = bx * 8;
  const int nocc = *noccPtr;

  for (int idx = t; idx < 4096; idx += 256) selsc[idx] = 0.f;
  if (t < 64) {
    int tok = t >> 3, h = t & 7;
    float lt = 0.f;
#pragma unroll
    for (int qq = 0; qq < 4; ++qq)
      lt += lpart[((size_t)qq * NT + n0 + tok) * 8 + h];
    rlh[tok][h] = 1.f / lt;
  }
  __syncthreads();

  const float* Sb = S + (size_t)bx * 64 * KPAD;   // rows (h*8 + tok)
  for (int tok = 0; tok < 8; ++tok) {
    for (int i0 = 0; i0 < nocc; i0 += 256) {
      int i = i0 + t;
      if (i < nocc) {
        float ps = 0.f;
#pragma unroll
        for (int h = 0; h < 8; ++h)
          ps += Sb[((size_t)h * 8 + tok) * KPAD + i] * rlh[tok][h];
        atomicAdd(&selsc[tok * 512 + sid_key[i]], ps);
      }
    }
  }
  __syncthreads();

  // fused = gate0 * (sum_q o_un) / l_tot
  for (int idx = t; idx < 4096; idx += 256) {
    int tok = idx >> 9, d = idx & 511, h = d >> 6;
    float osum = 0.f;
#pragma unroll
    for (int qq = 0; qq < 4; ++qq)
      osum += opart[((size_t)qq * NT + n0 + tok) * 512 + d];
    fused[(size_t)(n0 + tok) * 512 + d] = gates[(n0 + tok) * 3] * osum * rlh[tok][h];
  }

  // top-8 per token: 4 waves x 2 tokens (value desc, index asc ties)
  int w = t >> 6, l = t & 63;
  for (int tk2 = 0; tk2 < 2; ++tk2) {
    int tok = w * 2 + tk2;
    float* sp = selsc + tok * 512;
    float v[8];
#pragma unroll
    for (int r = 0; r < 8; ++r) v[r] = sp[r * 64 + l];
#pragma unroll
    for (int k = 0; k < 8; ++k) {
      float bv = v[0]; int bi = l;
#pragma unroll
      for (int r = 1; r < 8; ++r)
        if (v[r] > bv) { bv = v[r]; bi = r * 64 + l; }
#pragma unroll
      for (int s2 = 32; s2; s2 >>= 1) {
        float ov = __shfl_xor(bv, s2, 64);
        int oi = __shfl_xor(bi, s2, 64);
        if (ov > bv || (ov == bv && oi < bi)) { bv = ov; bi = oi; }
      }
      if (l == 0) topk_out[(n0 + tok) * 8 + k] = bi;
#pragma unroll
      for (int r = 0; r < 8; ++r)
        if (bi == r * 64 + l) v[r] = NEGI;
    }
  }
}

// =========================================================================
// selection + window attention (sparse, bucketed), adds into fused.
// float4-vectorized k/v/q access (2 b128 loads per key per array).
// =========================================================================
__global__ __launch_bounds__(64) void selwin(
    const float* __restrict__ q, const float* __restrict__ kf,
    const float* __restrict__ vf, const int* __restrict__ topk,
    const int* __restrict__ seloff, const int* __restrict__ sellist,
    const int* __restrict__ winoff, const int* __restrict__ winlist,
    const int* __restrict__ wid_tok, const float* __restrict__ gates,
    float* __restrict__ fused) {
  int n = blockIdx.x, t = threadIdx.x;
  int h = t >> 3, j = t & 7;
  const size_t lane_off = (size_t)h * 64 + j * 8;
  const float4* qp = (const float4*)(q + (size_t)n * 512 + lane_off);
  float4 qa = qp[0], qb = qp[1];

  // ---- selection branch ----
  float4 os0 = make_float4(0.f, 0.f, 0.f, 0.f);
  float4 os1 = make_float4(0.f, 0.f, 0.f, 0.f);
  float m = NEGI, lsum = 0.f;
  for (int k = 0; k < 8; ++k) {
    int s = topk[n * 8 + k];
    int e0 = seloff[s], e1 = seloff[s + 1];
    for (int idx = e0; idx < e1; ++idx) {
      int tj = sellist[idx];
      const float4* kp = (const float4*)(kf + (size_t)tj * 512 + lane_off);
      float4 ka = kp[0], kb = kp[1];
      float part = qa.x * ka.x + qa.y * ka.y + qa.z * ka.z + qa.w * ka.w
                 + qb.x * kb.x + qb.y * kb.y + qb.z * kb.z + qb.w * kb.w;
      part += __shfl_xor(part, 1, 64);
      part += __shfl_xor(part, 2, 64);
      part += __shfl_xor(part, 4, 64);
      float sc = part * 0.125f;
      float nm = fmaxf(m, sc);
      float scale = __expf(m - nm);
      float pv = __expf(sc - nm);
      const float4* vp = (const float4*)(vf + (size_t)tj * 512 + lane_off);
      float4 va = vp[0], vb = vp[1];
      lsum = lsum * scale + pv;
      os0.x = os0.x * scale + pv * va.x; os0.y = os0.y * scale + pv * va.y;
      os0.z = os0.z * scale + pv * va.z; os0.w = os0.w * scale + pv * va.w;
      os1.x = os1.x * scale + pv * vb.x; os1.y = os1.y * scale + pv * vb.y;
      os1.z = os1.z * scale + pv * vb.z; os1.w = os1.w * scale + pv * vb.w;
      m = nm;
    }
  }
  {
    float rl = (lsum > 0.f) ? 1.f / lsum : 0.f;
    os0.x *= rl; os0.y *= rl; os0.z *= rl; os0.w *= rl;
    os1.x *= rl; os1.y *= rl; os1.z *= rl; os1.w *= rl;
  }

  // ---- window branch ----
  float4 ow0 = make_float4(0.f, 0.f, 0.f, 0.f);
  float4 ow1 = make_float4(0.f, 0.f, 0.f, 0.f);
  m = NEGI; lsum = 0.f;
  int w = wid_tok[n];
  int e0 = winoff[w], e1 = winoff[w + 1];
  for (int idx = e0; idx < e1; ++idx) {
    int tj = winlist[idx];
    const float4* kp = (const float4*)(kf + (size_t)tj * 512 + lane_off);
    float4 ka = kp[0], kb = kp[1];
    float part = qa.x * ka.x + qa.y * ka.y + qa.z * ka.z + qa.w * ka.w
               + qb.x * kb.x + qb.y * kb.y + qb.z * kb.z + qb.w * kb.w;
    part += __shfl_xor(part, 1, 64);
    part += __shfl_xor(part, 2, 64);
    part += __shfl_xor(part, 4, 64);
    float sc = part * 0.125f;
    float nm = fmaxf(m, sc);
    float scale = __expf(m - nm);
    float pv = __expf(sc - nm);
    const float4* vp = (const float4*)(vf + (size_t)tj * 512 + lane_off);
    float4 va = vp[0], vb = vp[1];
    lsum = lsum * scale + pv;
    ow0.x = ow0.x * scale + pv * va.x; ow0.y = ow0.y * scale + pv * va.y;
    ow0.z = ow0.z * scale + pv * va.z; ow0.w = ow0.w * scale + pv * va.w;
    ow1.x = ow1.x * scale + pv * vb.x; ow1.y = ow1.y * scale + pv * vb.y;
    ow1.z = ow1.z * scale + pv * vb.z; ow1.w = ow1.w * scale + pv * vb.w;
    m = nm;
  }
  {
    float rl = (lsum > 0.f) ? 1.f / lsum : 0.f;
    ow0.x *= rl; ow0.y *= rl; ow0.z *= rl; ow0.w *= rl;
    ow1.x *= rl; ow1.y *= rl; ow1.z *= rl; ow1.w *= rl;
  }

  float g1 = gates[n * 3 + 1], g2 = gates[n * 3 + 2];
  float4* fp = (float4*)(fused + (size_t)n * 512 + lane_off);
  float4 f0 = fp[0], f1 = fp[1];
  f0.x += g1 * os0.x + g2 * ow0.x; f0.y += g1 * os0.y + g2 * ow0.y;
  f0.z += g1 * os0.z + g2 * ow0.z; f0.w += g1 * os0.w + g2 * ow0.w;
  f1.x += g1 * os1.x + g2 * ow1.x; f1.y += g1 * os1.y + g2 * ow1.y;
  f1.z += g1 * os1.z + g2 * ow1.z; f1.w += g1 * os1.w + g2 * ow1.w;
  fp[0] = f0; fp[1] = f1;
}

// =========================================================================
// launcher
// =========================================================================
extern "C" void kernel_launch(void* const* d_in, const int* in_sizes, int n_in,
                              void* d_out, int out_size, void* d_ws, size_t ws_size,
                              hipStream_t stream) {
  const float* feats = (const float*)d_in[0];
  const int* coords  = (const int*)d_in[1];
  const float* Wq  = (const float*)d_in[2];
  const float* Wk  = (const float*)d_in[3];
  const float* Wv  = (const float*)d_in[4];
  const float* Wo  = (const float*)d_in[5];
  const float* Wck = (const float*)d_in[6];
  const float* Wcv = (const float*)d_in[7];
  const float* pe  = (const float*)d_in[8];
  const float* Wg  = (const float*)d_in[9];
  float* out = (float*)d_out;

  char* p = (char*)d_ws;
  auto alloc = [&](size_t bytes) -> char* {
    char* r = p;
    p += (bytes + 255) & ~(size_t)255;
    return r;
  };
  float* q     = (float*)alloc((size_t)NT * 512 * 4);
  float* kf    = (float*)alloc((size_t)NT * 512 * 4);
  float* vf    = (float*)alloc((size_t)NT * 512 * 4);
  float* fused = (float*)alloc((size_t)NT * 512 * 4);
  float* zf    = (float*)alloc((size_t)2 * NT * 512 * 4);  // ckbar|cvbar (zeroed)
  float* ckbar = zf;
  float* cvbar = zf + (size_t)NT * 512;
  float* ckc   = (float*)alloc((size_t)NT * 512 * 4);
  float* cvc   = (float*)alloc((size_t)NT * 512 * 4);
  float* ckT   = (float*)alloc((size_t)512 * KPAD * 4);
  float* gates = (float*)alloc((size_t)NT * 3 * 4);
  float* lpart = (float*)alloc((size_t)4 * NT * 8 * 4);
  float* opart = (float*)alloc((size_t)4 * NT * 512 * 4);
  int* zi      = (int*)alloc((size_t)(MBLK + SBLK + NW3) * 4);  // cnt|selcnt|wincnt
  int* cnt = zi;
  int* selcnt = zi + MBLK;
  int* wincnt = zi + MBLK + SBLK;
  int* inv     = (int*)alloc((size_t)MBLK * 4);
  int* occ     = (int*)alloc((size_t)NT * 4);
  int* nocc    = (int*)alloc(4);
  int* bid     = (int*)alloc((size_t)NT * 4);
  int* sbid    = (int*)alloc((size_t)NT * 4);
  int* wid     = (int*)alloc((size_t)NT * 4);
  int* ibid    = (int*)alloc((size_t)NT * 4);
  int* sid_key = (int*)alloc((size_t)NT * 4);
  int* seloff  = (int*)alloc((size_t)(SBLK + 1) * 4);
  int* selpos  = (int*)alloc((size_t)SBLK * 4);
  int* sellist = (int*)alloc((size_t)NT * 4);
  int* winoff  = (int*)alloc((size_t)(NW3 + 1) * 4);
  int* winpos  = (int*)alloc((size_t)NW3 * 4);
  int* winlist = (int*)alloc((size_t)NT * 4);
  int* topk    = (int*)alloc((size_t)NT * 8 * 4);
  // big S buffer last: 256 groups x 64 rows x KPAD f32 = 128 MB
  size_t sbytes = (size_t)(NT / 8) * 64 * KPAD * 4;
  float* S = (float*)alloc(sbytes);

  hipMemsetAsync(zf, 0, (size_t)2 * NT * 512 * 4, stream);
  hipMemsetAsync(zi, 0, (size_t)(MBLK + SBLK + NW3) * 4, stream);

  token_prep<<<8, 256, 0, stream>>>(coords, bid, sbid, wid, ibid, cnt, selcnt, wincnt);
  scan_all<<<1, 1024, 0, stream>>>(cnt, occ, inv, nocc, selcnt, seloff, selpos,
                                   wincnt, winoff, winpos);
  scatter<<<8, 256, 0, stream>>>(sbid, wid, selpos, winpos, sellist, winlist);

  gemm512_b3<<<dim3(32, 8, 3), 256, 0, stream>>>(feats, Wq, Wk, Wv, q, kf, vf);
  gatek<<<24, 256, 0, stream>>>(feats, Wg, gates);

  accum<<<NT, 256, 0, stream>>>(kf, vf, pe, bid, ibid, inv, ckbar, cvbar);
  divide_means<<<4096, 256, 0, stream>>>(ckbar, cvbar, occ, cnt, nocc, sid_key);
  gemm512_b2<<<dim3(32, 8, 2), 256, 0, stream>>>(ckbar, cvbar, Wck, Wcv, ckc, cvc, nocc);
  transp<<<dim3(32, 8), 256, 0, stream>>>(ckc, ckT, nocc);

  cqkpv<<<dim3(256, 4), 512, 0, stream>>>(q, ckT, cvc, nocc, S, lpart, opart);
  cselfin<<<256, 256, 0, stream>>>(S, lpart, opart, sid_key, nocc, gates,
                                   fused, topk);

  selwin<<<NT, 64, 0, stream>>>(q, kf, vf, topk, seloff, sellist, winoff, winlist,
                                wid, gates, fused);
  gemm512<<<dim3(32, 8), 256, 0, stream>>>(fused, Wo, out, NT);
}